// Round 10
// baseline (389.200 us; speedup 1.0000x reference)
//
#include <hip/hip_runtime.h>

#define NE 50000
#define NN 10000
#define KH 96          // real K: 96 (bias injected in dequant epilogue)
#define WN 6928
#define NTILE 484
#define IN_SZ 156
#define EPW 32         // edges per workgroup in tp_kernel

typedef __attribute__((ext_vector_type(8))) short short8;
typedef __attribute__((ext_vector_type(4))) float float4v;
typedef __attribute__((ext_vector_type(4))) int int4v;
typedef __attribute__((ext_vector_type(2))) float float2v;
typedef __attribute__((ext_vector_type(2))) long long2v;

__device__ __forceinline__ unsigned short f2bf(float x) {
  unsigned u = __float_as_uint(x);
  unsigned r = (u + 0x7FFFu + ((u >> 16) & 1u)) >> 16;   // RNE
  return (unsigned short)r;
}
__device__ __forceinline__ float b2f(unsigned short u) {
  return __uint_as_float(((unsigned)u) << 16);
}
__device__ __forceinline__ unsigned char q8(float x, float inv) {
  return (unsigned char)(signed char)__float2int_rn(fminf(fmaxf(x * inv, -127.f), 127.f));
}
__device__ __forceinline__ unsigned p4(unsigned a, unsigned b, unsigned c, unsigned d) {
  return a | (b << 8) | (c << 16) | (d << 24);
}

// ---- forced-pipeline primitives: volatile asm loads + explicit vmcnt ----
// One i8 B tile = 16 cols x 96 k x 1B = 1536B in W2PT8:
//   partA [0,1024):    lane*16 = [s0 frag 8B | s1 frag 8B]  (dwordx4, 1KB coalesced)
//   partB [1024,1536): lane*8  = [s2 frag 8B]               (dwordx2, 512B)
// 3rd op = this tile-col's {b2, colscale} float2 (dwordx2).
// 3 VMEM ops per tile -> vmcnt 6/3/0 for 3-deep, 3/0 for 2-deep.
// NOTE: asm-tied regs are async load destinations — never tighten launch
// bounds into spill range (r2 abort, r6 corruption).
__device__ __forceinline__ void issueT(long2v &W01, long &W2f, float2v &bs,
                                       const unsigned char* pA,
                                       const unsigned char* pB,
                                       const float* pbs) {
  asm volatile("global_load_dwordx4 %0, %3, off\n\t"
               "global_load_dwordx2 %1, %4, off\n\t"
               "global_load_dwordx2 %2, %5, off"
               : "=&v"(W01), "=&v"(W2f), "=&v"(bs)
               : "v"(pA), "v"(pB), "v"(pbs));
}
__device__ __forceinline__ void waitT6(long2v &W01, long &W2f, float2v &bs) {
  asm volatile("s_waitcnt vmcnt(6)" : "+v"(W01), "+v"(W2f), "+v"(bs));
}
__device__ __forceinline__ void waitT3(long2v &W01, long &W2f, float2v &bs) {
  asm volatile("s_waitcnt vmcnt(3)" : "+v"(W01), "+v"(W2f), "+v"(bs));
}
__device__ __forceinline__ void waitT0(long2v &W01, long &W2f, float2v &bs) {
  asm volatile("s_waitcnt vmcnt(0)" : "+v"(W01), "+v"(W2f), "+v"(bs));
}

// permuted column index np -> original W2 column c (or -1 for pad lanes)
__device__ __forceinline__ int col_of_np(int np) {
  if (np < 2784) return np;
  if (np < 3872) { int rel = np - 2784, i = rel >> 4, o = rel & 15; return (o < 10) ? 2784 + i * 10 + o : -1; }
  if (np < 4960) { int rel = np - 3872, i = rel >> 4, o = rel & 15; return (o < 10) ? 3464 + i * 10 + o : -1; }
  return 4144 + (np - 4960);
}

// ---------------- Kernel P: all preprocessing in one dispatch ----------------
// regions: [0,R0) one thread per W2 column: colmax -> i8 pack + {b2,sc} |
// [R0,R1) W1T | [R1,R2) acc=0 | [R2,R3) icnt=0 | [R3,R4) h8 pad | [R4,R5) hscale pad
#define R0 (NTILE * 16)
#define R1 (R0 + KH * KH)
#define R2 (R1 + NN * IN_SZ / 4)
#define R3 (R2 + NN / 4)
#define R4 (R3 + 96)
#define R5 (R4 + 4)
__global__ __launch_bounds__(256) void prep_kernel(
    const float* __restrict__ W2, const float* __restrict__ b2,
    const float* __restrict__ W1,
    unsigned char* __restrict__ W2PT8, float2v* __restrict__ bscPT,
    unsigned short* __restrict__ W1T,
    float* __restrict__ acc, int* __restrict__ icnt,
    unsigned char* __restrict__ h8, float* __restrict__ hscale)
{
  int gid = blockIdx.x * 256 + threadIdx.x;
  if (gid < R0) {
    int np = gid, t = np >> 4, l = np & 15;
    int c = col_of_np(np);
    float m = 0.f;
    if (c >= 0) {
      #pragma unroll 1
      for (int k = 0; k < KH; ++k) m = fmaxf(m, fabsf(W2[(size_t)k * WN + c]));
    }
    float sc = m / 127.f;
    float inv = (m > 0.f) ? 127.f / m : 0.f;
    float2v bs; bs.x = (c >= 0) ? b2[c] : 0.f; bs.y = sc;
    bscPT[np] = bs;
    #pragma unroll 1
    for (int qq = 0; qq < 4; ++qq) {
      unsigned char bb[24];
      #pragma unroll
      for (int j = 0; j < 8; ++j) {
        int k0 = qq * 8 + j;
        bb[j]      = q8((c >= 0) ? W2[(size_t)k0 * WN + c] : 0.f, inv);
        bb[8 + j]  = q8((c >= 0) ? W2[(size_t)(32 + k0) * WN + c] : 0.f, inv);
        bb[16 + j] = q8((c >= 0) ? W2[(size_t)(64 + k0) * WN + c] : 0.f, inv);
      }
      uint4 pa;
      pa.x = p4(bb[0], bb[1], bb[2], bb[3]);
      pa.y = p4(bb[4], bb[5], bb[6], bb[7]);
      pa.z = p4(bb[8], bb[9], bb[10], bb[11]);
      pa.w = p4(bb[12], bb[13], bb[14], bb[15]);
      *(uint4*)(W2PT8 + (size_t)t * 1536 + (qq * 16 + l) * 16) = pa;
      uint2 pb;
      pb.x = p4(bb[16], bb[17], bb[18], bb[19]);
      pb.y = p4(bb[20], bb[21], bb[22], bb[23]);
      *(uint2*)(W2PT8 + (size_t)t * 1536 + 1024 + (qq * 16 + l) * 8) = pb;
    }
  } else if (gid < R1) {
    int j = gid - R0;
    int c = j / KH, k = j - c * KH;
    W1T[c * KH + k] = f2bf(W1[k * KH + c]);   // W1T[col][k]
  } else if (gid < R2) {
    uint4 z = {0, 0, 0, 0};
    ((uint4*)acc)[gid - R1] = z;
  } else if (gid < R3) {
    uint4 z = {0, 0, 0, 0};
    ((uint4*)icnt)[gid - R2] = z;
  } else if (gid < R4) {
    uint4 z = {0, 0, 0, 0};
    ((uint4*)(h8 + (size_t)NE * KH))[gid - R3] = z;
  } else if (gid < R5) {
    uint4 z = {0, 0, 0, 0};
    ((uint4*)(hscale + NE))[gid - R4] = z;
  }
}

// ---------------- Kernel 1: h = relu(ea @ W1 + b1) -> i8 with per-row scale ----------------
__global__ __launch_bounds__(384) void mlp1_kernel(
    const float* __restrict__ edge_attr, const unsigned short* __restrict__ W1T,
    const float* __restrict__ b1, unsigned char* __restrict__ h8,
    float* __restrict__ hscale)
{
  __shared__ unsigned rmax[16];
  const int tid = threadIdx.x;
  const int e0 = blockIdx.x * 16;
  const int w = tid >> 6, l = tid & 15, q = (tid >> 4) & 3;
  if (tid < 16) rmax[tid] = 0;

  short8 a[3], b[3];
  #pragma unroll
  for (int s = 0; s < 3; ++s) {
    const float* pa = edge_attr + (size_t)(e0 + l) * KH + s * 32 + q * 8;
    float4 x = *(const float4*)pa, y = *(const float4*)(pa + 4);
    short8 t;
    t[0] = (short)f2bf(x.x); t[1] = (short)f2bf(x.y);
    t[2] = (short)f2bf(x.z); t[3] = (short)f2bf(x.w);
    t[4] = (short)f2bf(y.x); t[5] = (short)f2bf(y.y);
    t[6] = (short)f2bf(y.z); t[7] = (short)f2bf(y.w);
    a[s] = t;
    b[s] = *(const short8*)(W1T + (size_t)(w * 16 + l) * KH + s * 32 + q * 8);
  }
  float4v C = {0.f, 0.f, 0.f, 0.f};
  #pragma unroll
  for (int s = 0; s < 3; ++s)
    C = __builtin_amdgcn_mfma_f32_16x16x32_bf16(a[s], b[s], C, 0, 0, 0);

  float bv = b1[w * 16 + l];
  float v[4];
  #pragma unroll
  for (int r = 0; r < 4; ++r) v[r] = fmaxf(C[r] + bv, 0.f);
  __syncthreads();                 // rmax init visible
  #pragma unroll
  for (int r = 0; r < 4; ++r) atomicMax(&rmax[q * 4 + r], __float_as_uint(v[r]));
  __syncthreads();
  #pragma unroll
  for (int r = 0; r < 4; ++r) {
    float m = __uint_as_float(rmax[q * 4 + r]);
    float inv = (m > 0.f) ? 127.f / m : 0.f;
    h8[(size_t)(e0 + q * 4 + r) * KH + w * 16 + l] =
        (unsigned char)__float2int_rn(v[r] * inv);
  }
  if (w == 0 && l == 0) {
    #pragma unroll
    for (int r = 0; r < 4; ++r)
      hscale[e0 + q * 4 + r] = __uint_as_float(rmax[q * 4 + r]) / 127.f;
  }
}

// ---------------- Kernel 2: i8 MFMA w-GEMM fused with TP ----------------
// r1 structure exactly (EPW=32, 2 blocks/CU, sIn/sOut staging, 3-deep scalar
// + 2-deep vector pipelines) with HALF the B-tile bytes via i8: same
// outstanding-request count, half the L2 service demand. Dequant epilogue:
// out = (float)i32acc * sc * se[row] + b2, then * feature.
__global__ __launch_bounds__(512, 2) void tp_kernel(
    const unsigned char* __restrict__ h8, const float* __restrict__ node_attr,
    const int* __restrict__ edge_index, const float* __restrict__ edge_sh,
    const unsigned char* __restrict__ W2PT8, const float2v* __restrict__ bscPT,
    const float* __restrict__ hscale,
    float* __restrict__ acc, int* __restrict__ icnt)
{
  __shared__ unsigned short sIn[EPW][160];         // bf16 gathered node_attr
  __shared__ float sOut[EPW][IN_SZ];               // f32 output staging
  __shared__ unsigned short sF0[2][60][EPW];       // scalar feats; rows 58,59 = 0
  __shared__ unsigned short sF1[2][68][3][EPW];    // vector feats
  __shared__ float sShs[EPW][4];
  __shared__ int sSrc[EPW], sDst[EPW];
  // LDS total = 10240+19968+7680+26112+512+256 = 64768 B -> 2 blocks/CU

  const int tid = threadIdx.x;
  const int e0 = blockIdx.x * EPW;

  if (tid < EPW) {
    int ok = (e0 + tid) < NE;
    int s = ok ? edge_index[e0 + tid] : 0;
    int d = ok ? edge_index[NE + e0 + tid] : 0;
    sSrc[tid] = s; sDst[tid] = d;
    if (ok) atomicAdd(&icnt[s], 1);
  }
  if (tid >= 128 && tid < 256) {
    int t2 = tid - 128;
    int e = t2 >> 2, c = t2 & 3;
    sShs[e][c] = ((e0 + e) < NE) ? edge_sh[(size_t)(e0 + e) * 4 + c] : 0.f;
  }
  __syncthreads();

  // coalesced gather of node_attr rows into LDS
  for (int idx = tid; idx < EPW * IN_SZ; idx += 512) {
    int e = idx / IN_SZ, f = idx - e * IN_SZ;
    sIn[e][f] = f2bf(node_attr[(size_t)sDst[e] * IN_SZ + f]);
  }
  for (int idx = tid; idx < EPW * IN_SZ; idx += 512) (&sOut[0][0])[idx] = 0.f;
  __syncthreads();

  { // ---- feature construction: 16 workers per edge ----
    const int e = tid >> 4, j = tid & 15;
    const float sh0 = sShs[e][0], sx = sShs[e][1], sy = sShs[e][2], sz = sShs[e][3];
    const float i3 = 0.57735026918962576f, i2 = 0.70710678118654752f;
    for (int i = j; i < 48; i += 16) {
      float v0 = b2f(sIn[e][i]), w0 = b2f(sIn[e][108 + i]);
      sF0[0][i][e] = f2bf(v0 * sh0);
      sF0[1][10 + i][e] = f2bf(w0 * sh0);
      sF1[0][i][0][e] = f2bf(v0 * sx); sF1[0][i][1][e] = f2bf(v0 * sy); sF1[0][i][2][e] = f2bf(v0 * sz);
      sF1[1][20 + i][0][e] = f2bf(w0 * sx); sF1[1][20 + i][1][e] = f2bf(w0 * sy); sF1[1][20 + i][2][e] = f2bf(w0 * sz);
    }
    if (j < 10) {
      const int v = j;
      float ax = b2f(sIn[e][48 + 3 * v]), ay = b2f(sIn[e][48 + 3 * v + 1]), az = b2f(sIn[e][48 + 3 * v + 2]);
      float bx = b2f(sIn[e][78 + 3 * v]), by = b2f(sIn[e][78 + 3 * v + 1]), bz = b2f(sIn[e][78 + 3 * v + 2]);
      sF0[0][48 + v][e] = f2bf((ax * sx + ay * sy + az * sz) * i3);
      sF0[1][v][e]      = f2bf((bx * sx + by * sy + bz * sz) * i3);
      sF1[0][48 + v][0][e] = f2bf(ax * sh0); sF1[0][48 + v][1][e] = f2bf(ay * sh0); sF1[0][48 + v][2][e] = f2bf(az * sh0);
      sF1[0][58 + v][0][e] = f2bf((by * sz - bz * sy) * i2);
      sF1[0][58 + v][1][e] = f2bf((bz * sx - bx * sz) * i2);
      sF1[0][58 + v][2][e] = f2bf((bx * sy - by * sx) * i2);
      sF1[1][v][0][e] = f2bf((ay * sz - az * sy) * i2);
      sF1[1][v][1][e] = f2bf((az * sx - ax * sz) * i2);
      sF1[1][v][2][e] = f2bf((ax * sy - ay * sx) * i2);
      sF1[1][10 + v][0][e] = f2bf(bx * sh0); sF1[1][10 + v][1][e] = f2bf(by * sh0); sF1[1][10 + v][2][e] = f2bf(bz * sh0);
    }
  }
  // zero sF0 pad rows 58,59 (scalar upper-half waves read them with f=0)
  if (tid < 128) {
    int fam = tid >> 6, i = 58 + ((tid >> 5) & 1), e = tid & 31;
    sF0[fam][i][e] = 0;
  }
  __syncthreads();

  const int wv = tid >> 6, l = tid & 15, q = (tid >> 4) & 3;

  // A fragments (i8): per lane 8 bytes = k s*32+q*8..+7 of row.
  long Af[2][3];
  float se0[4], se1[4];          // per-row dequant scales for both edge halves
  #pragma unroll
  for (int m = 0; m < 2; ++m) {
    const unsigned char* ar = h8 + (size_t)(e0 + m * 16 + l) * KH + q * 8;
    #pragma unroll
    for (int s = 0; s < 3; ++s) Af[m][s] = *(const long*)(ar + s * 32);
  }
  #pragma unroll
  for (int r = 0; r < 4; ++r) {
    se0[r] = hscale[e0 + q * 4 + r];
    se1[r] = hscale[e0 + 16 + q * 4 + r];
  }

  const unsigned char* wlaneA = W2PT8 + (size_t)(tid & 63) * 16;
  const unsigned char* wlaneB = W2PT8 + 1024 + (size_t)(tid & 63) * 8;
  const float* bslane = (const float*)(bscPT + l);

  // one i8-MFMA body for scalar families
  auto sbody = [&](float (&a0)[4], float (&a1)[4],
                   const long2v &W01, const long &W2f, const float2v &bs,
                   int sf, int i) {
    ushort4 f0 = *(const ushort4*)&sF0[sf][i][q * 4];
    ushort4 f1 = *(const ushort4*)&sF0[sf][i][16 + q * 4];
    int4v C0 = {0, 0, 0, 0}, C1 = {0, 0, 0, 0};
    C0 = __builtin_amdgcn_mfma_i32_16x16x32_i8(Af[0][0], W01.x, C0, 0, 0, 0);
    C1 = __builtin_amdgcn_mfma_i32_16x16x32_i8(Af[1][0], W01.x, C1, 0, 0, 0);
    C0 = __builtin_amdgcn_mfma_i32_16x16x32_i8(Af[0][1], W01.y, C0, 0, 0, 0);
    C1 = __builtin_amdgcn_mfma_i32_16x16x32_i8(Af[1][1], W01.y, C1, 0, 0, 0);
    C0 = __builtin_amdgcn_mfma_i32_16x16x32_i8(Af[0][2], W2f, C0, 0, 0, 0);
    C1 = __builtin_amdgcn_mfma_i32_16x16x32_i8(Af[1][2], W2f, C1, 0, 0, 0);
    const float bv = bs.x, sc = bs.y;
    float u;
    u = fmaf((float)C0[0], sc * se0[0], bv); a0[0] = fmaf(u, b2f(f0.x), a0[0]);
    u = fmaf((float)C0[1], sc * se0[1], bv); a0[1] = fmaf(u, b2f(f0.y), a0[1]);
    u = fmaf((float)C0[2], sc * se0[2], bv); a0[2] = fmaf(u, b2f(f0.z), a0[2]);
    u = fmaf((float)C0[3], sc * se0[3], bv); a0[3] = fmaf(u, b2f(f0.w), a0[3]);
    u = fmaf((float)C1[0], sc * se1[0], bv); a1[0] = fmaf(u, b2f(f1.x), a1[0]);
    u = fmaf((float)C1[1], sc * se1[1], bv); a1[1] = fmaf(u, b2f(f1.y), a1[1]);
    u = fmaf((float)C1[2], sc * se1[2], bv); a1[2] = fmaf(u, b2f(f1.z), a1[2]);
    u = fmaf((float)C1[3], sc * se1[3], bv); a1[3] = fmaf(u, b2f(f1.w), a1[3]);
  };

  if (wv < 4) {
    // ---------------- scalar families (0e / 0o): 3 ob-phases x 30 i, 3-deep ----------------
    const int sf = wv >> 1;
    const int ibeg = (wv & 1) * 30;
    const int tb = sf ? 310 : 0;
    const int obase = sf ? 108 : 0;
    #pragma unroll 1
    for (int ob = 0; ob < 3; ++ob) {
      float a0[4] = {0.f, 0.f, 0.f, 0.f}, a1[4] = {0.f, 0.f, 0.f, 0.f};
      long2v Wa01, Wb01, Wc01; long Wa2, Wb2, Wc2; float2v vA, vB, vC;
      auto tadr = [&](int ii) -> size_t {
        int i = ibeg + ii; if (i >= 58) i = ibeg;     // pad rows load a safe tile (f=0)
        return (size_t)(tb + 3 * i + ob);
      };
      { size_t t = tadr(0); issueT(Wa01, Wa2, vA, wlaneA + t * 1536, wlaneB + t * 1536, bslane + t * 32); }
      { size_t t = tadr(1); issueT(Wb01, Wb2, vB, wlaneA + t * 1536, wlaneB + t * 1536, bslane + t * 32); }
      { size_t t = tadr(2); issueT(Wc01, Wc2, vC, wlaneA + t * 1536, wlaneB + t * 1536, bslane + t * 32); }
      #pragma unroll 1
      for (int ii = 0; ii < 27; ii += 3) {
        waitT6(Wa01, Wa2, vA); sbody(a0, a1, Wa01, Wa2, vA, sf, ibeg + ii);
        { size_t t = tadr(ii + 3); issueT(Wa01, Wa2, vA, wlaneA + t * 1536, wlaneB + t * 1536, bslane + t * 32); }
        waitT6(Wb01, Wb2, vB); sbody(a0, a1, Wb01, Wb2, vB, sf, ibeg + ii + 1);
        { size_t t = tadr(ii + 4); issueT(Wb01, Wb2, vB, wlaneA + t * 1536, wlaneB + t * 1536, bslane + t * 32); }
        waitT6(Wc01, Wc2, vC); sbody(a0, a1, Wc01, Wc2, vC, sf, ibeg + ii + 2);
        { size_t t = tadr(ii + 5); issueT(Wc01, Wc2, vC, wlaneA + t * 1536, wlaneB + t * 1536, bslane + t * 32); }
      }
      waitT6(Wa01, Wa2, vA); sbody(a0, a1, Wa01, Wa2, vA, sf, ibeg + 27);
      waitT3(Wb01, Wb2, vB); sbody(a0, a1, Wb01, Wb2, vB, sf, ibeg + 28);
      waitT0(Wc01, Wc2, vC); sbody(a0, a1, Wc01, Wc2, vC, sf, ibeg + 29);
      const int col = obase + ob * 16 + l;
      #pragma unroll
      for (int r = 0; r < 4; ++r) {
        unsafeAtomicAdd(&sOut[q * 4 + r][col],      a0[r]);
        unsafeAtomicAdd(&sOut[16 + q * 4 + r][col], a1[r]);
      }
    }
  } else {
    // ---------------- vector families (1o / 1e): i-half 34 bodies, 2-deep ----------------
    const int vf = (wv >> 1) - 2;
    const int ibeg = (wv & 1) * 34;
    const int tb = vf ? 242 : 174;
    float r0[4][3] = {{0.f}}, r1[4][3] = {{0.f}};
    long2v Wa01, Wb01; long Wa2, Wb2; float2v vA, vB;
    auto tadr = [&](int ii) -> size_t { return (size_t)(tb + ibeg + ii); };
    auto vbody = [&](const long2v &W01, const long &W2f, const float2v &bs, int ii) {
      int i = ibeg + ii;
      ushort4 g0[3], g1[3];
      #pragma unroll
      for (int cc = 0; cc < 3; ++cc) {
        g0[cc] = *(const ushort4*)&sF1[vf][i][cc][q * 4];
        g1[cc] = *(const ushort4*)&sF1[vf][i][cc][16 + q * 4];
      }
      int4v C0 = {0, 0, 0, 0}, C1 = {0, 0, 0, 0};
      C0 = __builtin_amdgcn_mfma_i32_16x16x32_i8(Af[0][0], W01.x, C0, 0, 0, 0);
      C1 = __builtin_amdgcn_mfma_i32_16x16x32_i8(Af[1][0], W01.x, C1, 0, 0, 0);
      C0 = __builtin_amdgcn_mfma_i32_16x16x32_i8(Af[0][1], W01.y, C0, 0, 0, 0);
      C1 = __builtin_amdgcn_mfma_i32_16x16x32_i8(Af[1][1], W01.y, C1, 0, 0, 0);
      C0 = __builtin_amdgcn_mfma_i32_16x16x32_i8(Af[0][2], W2f, C0, 0, 0, 0);
      C1 = __builtin_amdgcn_mfma_i32_16x16x32_i8(Af[1][2], W2f, C1, 0, 0, 0);
      const float bv = bs.x, sc = bs.y;
      float u0[4], u1[4];
      #pragma unroll
      for (int r = 0; r < 4; ++r) {
        u0[r] = fmaf((float)C0[r], sc * se0[r], bv);
        u1[r] = fmaf((float)C1[r], sc * se1[r], bv);
      }
      #pragma unroll
      for (int cc = 0; cc < 3; ++cc) {
        r0[0][cc] = fmaf(u0[0], b2f(g0[cc].x), r0[0][cc]);
        r0[1][cc] = fmaf(u0[1], b2f(g0[cc].y), r0[1][cc]);
        r0[2][cc] = fmaf(u0[2], b2f(g0[cc].z), r0[2][cc]);
        r0[3][cc] = fmaf(u0[3], b2f(g0[cc].w), r0[3][cc]);
        r1[0][cc] = fmaf(u1[0], b2f(g1[cc].x), r1[0][cc]);
        r1[1][cc] = fmaf(u1[1], b2f(g1[cc].y), r1[1][cc]);
        r1[2][cc] = fmaf(u1[2], b2f(g1[cc].z), r1[2][cc]);
        r1[3][cc] = fmaf(u1[3], b2f(g1[cc].w), r1[3][cc]);
      }
    };
    { size_t t = tadr(0); issueT(Wa01, Wa2, vA, wlaneA + t * 1536, wlaneB + t * 1536, bslane + t * 32); }
    { size_t t = tadr(1); issueT(Wb01, Wb2, vB, wlaneA + t * 1536, wlaneB + t * 1536, bslane + t * 32); }
    #pragma unroll 1
    for (int ii = 0; ii < 32; ii += 2) {
      waitT3(Wa01, Wa2, vA); vbody(Wa01, Wa2, vA, ii);
      { size_t t = tadr(ii + 2); issueT(Wa01, Wa2, vA, wlaneA + t * 1536, wlaneB + t * 1536, bslane + t * 32); }
      waitT3(Wb01, Wb2, vB); vbody(Wb01, Wb2, vB, ii + 1);
      { size_t t = tadr(ii + 3); issueT(Wb01, Wb2, vB, wlaneA + t * 1536, wlaneB + t * 1536, bslane + t * 32); }
    }
    waitT3(Wa01, Wa2, vA); vbody(Wa01, Wa2, vA, 32);
    waitT0(Wb01, Wb2, vB); vbody(Wb01, Wb2, vB, 33);
    if (l < 10) {
      const int col = (vf ? 78 : 48) + 3 * l;
      #pragma unroll
      for (int r = 0; r < 4; ++r)
        #pragma unroll
        for (int cc = 0; cc < 3; ++cc) {
          unsafeAtomicAdd(&sOut[q * 4 + r][col + cc], r0[r][cc]);
          unsafeAtomicAdd(&sOut[16 + q * 4 + r][col + cc], r1[r][cc]);
        }
    }
  }
  __syncthreads();

  // ---- scatter to global ----
  const float n58 = 0.13130643285972254f, n68 = 0.12126781251816650f;
  for (int idx = tid; idx < EPW * IN_SZ; idx += 512) {
    int e = idx / IN_SZ, o = idx - e * IN_SZ;
    if (e0 + e < NE) {
      float nrm = (o < 48 || o >= 108) ? n58 : n68;
      unsafeAtomicAdd(&acc[(size_t)sSrc[e] * IN_SZ + o], sOut[e][o] * nrm);
    }
  }
}

// ---------------- Kernel 3: out = acc / max(cnt,1) + node_attr ----------------
__global__ __launch_bounds__(256) void finalize_kernel(
    const float* __restrict__ acc, const int* __restrict__ icnt,
    const float* __restrict__ node_attr, float* __restrict__ out)
{
  int idx = blockIdx.x * 256 + threadIdx.x;
  if (idx < NN * IN_SZ) {
    int n = idx / IN_SZ;
    out[idx] = acc[idx] / fmaxf((float)icnt[n], 1.f) + node_attr[idx];
  }
}

extern "C" void kernel_launch(void* const* d_in, const int* in_sizes, int n_in,
                              void* d_out, int out_size, void* d_ws, size_t ws_size,
                              hipStream_t stream)
{
  const float* node_attr  = (const float*)d_in[0];
  const int*   edge_index = (const int*)d_in[1];
  const float* edge_attr  = (const float*)d_in[2];
  const float* edge_sh    = (const float*)d_in[3];
  const float* W1 = (const float*)d_in[4];
  const float* b1 = (const float*)d_in[5];
  const float* W2 = (const float*)d_in[6];
  const float* b2 = (const float*)d_in[7];
  float* out = (float*)d_out;

  unsigned char* h8    = (unsigned char*)d_ws;                  // 50016 * 96 i8
  unsigned char* W2PT8 = h8 + (size_t)50016 * KH;               // 484 tiles * 1536 B
  float2v* bscPT = (float2v*)(W2PT8 + (size_t)NTILE * 1536);    // 7744 * {b2, sc}
  float* hscale = (float*)(bscPT + NTILE * 16);                 // 50016 f32
  float* acc  = hscale + 50016;                                 // NN * 156 f32
  int*   icnt = (int*)(acc + (size_t)NN * IN_SZ);               // NN i32
  unsigned short* W1T = (unsigned short*)(icnt + NN);           // 96*96 bf16

  prep_kernel<<<(R5 + 255) / 256, 256, 0, stream>>>(W2, b2, W1, W2PT8, bscPT, W1T,
                                                    acc, icnt, h8, hscale);
  mlp1_kernel<<<NE / 16, 384, 0, stream>>>(edge_attr, W1T, b1, h8, hscale);
  tp_kernel<<<(NE + EPW - 1) / EPW, 512, 0, stream>>>(h8, node_attr, edge_index,
                                                      edge_sh, W2PT8, bscPT, hscale,
                                                      acc, icnt);
  finalize_kernel<<<(NN * IN_SZ + 255) / 256, 256, 0, stream>>>(acc, icnt, node_attr, out);
}